// Round 2
// baseline (79.671 us; speedup 1.0000x reference)
//
#include <hip/hip_runtime.h>
#include <math.h>

#define NB 16
#define KB 32
#define KA 16

__device__ __forceinline__ float softplus_f(float v) {
    // numerically stable log(1 + exp(v)) == logaddexp(v, 0)
    return fmaxf(v, 0.0f) + log1pf(expf(-fabsf(v)));
}

__device__ __forceinline__ float rfl_f(float v) {
    // force wave-uniform value into an SGPR
    return __uint_as_float(__builtin_amdgcn_readfirstlane(__float_as_uint(v)));
}

__global__ __launch_bounds__(256, 8) void BucketAdjustedHinge_kernel(
    const float* __restrict__ x,
    const float* __restrict__ x_mins,
    const float* __restrict__ x_maxs,
    const float* __restrict__ clip_los,
    const float* __restrict__ clip_his,
    const float* __restrict__ base_knots,
    const float* __restrict__ base_raw_w,
    const float* __restrict__ base_bias,
    const float* __restrict__ adj_knots,
    const float* __restrict__ adj_raw_w,
    const float* __restrict__ adj_bias,
    const int*   __restrict__ bucket_idx,
    float*       __restrict__ out,
    int n)
{
    // Per-bucket packed state:
    //   s_prm[b]   = {a, c, Lb, Hb}:  x01 = clamp(fma(x,a,c), Lb, Hb)
    //   s_awv[b][0..3] = 16 softplus'd adj weights; s_awv[b][4].x = total bias
    // Stride 5 float4 = 80 B -> 20 dwords -> 2-way bank alias across buckets (free).
    __shared__ float4 s_prm[NB];
    __shared__ float4 s_awv[NB][5];

    const int tid = threadIdx.x;

    if (tid < NB) {
        const float mn = x_mins[tid], mx = x_maxs[tid];
        const float a = 1.0f / (mx - mn + 1e-12f);
        const float c = -mn * a;
        const float lo = clip_los[tid], hi = clip_his[tid];
        // fold clip bounds through the (monotone) affine map + final [0,1] clamp;
        // non-finite bound => no clipping on that side
        const float Lb = isfinite(lo) ? fminf(fmaxf(fmaf(lo, a, c), 0.0f), 1.0f) : 0.0f;
        const float Hb = isfinite(hi) ? fmaxf(fminf(fmaf(hi, a, c), 1.0f), 0.0f) : 1.0f;
        s_prm[tid] = make_float4(a, c, Lb, Hb);
        s_awv[tid][4] = make_float4(adj_bias[tid] + base_bias[0], 0.0f, 0.0f, 0.0f);
    }
    if (tid < NB * KA) {
        ((float*)&s_awv[tid >> 4][0])[tid & (KA - 1)] = softplus_f(adj_raw_w[tid]);
    }
    __syncthreads();

    // Wave-uniform base-spline constants -> SGPRs (readfirstlane). Each v_min /
    // v_fmac reads at most one SGPR, so both knot and weight can live scalar.
    float sbk[KB], sbw[KB], sak[KA];
    #pragma unroll
    for (int k = 0; k < KB; ++k) {
        sbk[k] = rfl_f(base_knots[k]);
        sbw[k] = rfl_f(softplus_f(base_raw_w[k]));
    }
    #pragma unroll
    for (int k = 0; k < KA; ++k) sak[k] = rfl_f(adj_knots[k]);

    const int n4 = n >> 2;
    const int stride = gridDim.x * blockDim.x;
    const float4* __restrict__ x4v = (const float4*)x;
    const int4*   __restrict__ b4v = (const int4*)bucket_idx;
    float4*       __restrict__ o4v = (float4*)out;

    for (int i = blockIdx.x * blockDim.x + tid; i < n4; i += stride) {
        const float4 xv = x4v[i];
        const int4   bv = b4v[i];
        const float xs[4] = {xv.x, xv.y, xv.z, xv.w};
        const int   bs[4] = {bv.x, bv.y, bv.z, bv.w};
        float ox[4];
        #pragma unroll
        for (int j = 0; j < 4; ++j) {
            const int b = bs[j];
            const float4 prm = s_prm[b];
            float v = fmaf(xs[j], prm.x, prm.y);
            v = fminf(fmaxf(v, prm.z), prm.w);

            const float4 w0 = s_awv[b][0];
            const float4 w1 = s_awv[b][1];
            const float4 w2 = s_awv[b][2];
            const float4 w3 = s_awv[b][3];
            float acc0 = s_awv[b][4].x;   // total bias
            float acc1 = 0.0f;

            #pragma unroll
            for (int k = 0; k < KB; k += 2) {
                acc0 = fmaf(sbw[k],     fminf(v, sbk[k]),     acc0);
                acc1 = fmaf(sbw[k + 1], fminf(v, sbk[k + 1]), acc1);
            }
            const float wa[KA] = {w0.x, w0.y, w0.z, w0.w,
                                  w1.x, w1.y, w1.z, w1.w,
                                  w2.x, w2.y, w2.z, w2.w,
                                  w3.x, w3.y, w3.z, w3.w};
            #pragma unroll
            for (int k = 0; k < KA; k += 2) {
                acc0 = fmaf(wa[k],     fminf(v, sak[k]),     acc0);
                acc1 = fmaf(wa[k + 1], fminf(v, sak[k + 1]), acc1);
            }
            ox[j] = acc0 + acc1;
        }
        o4v[i] = make_float4(ox[0], ox[1], ox[2], ox[3]);
    }

    // tail (n % 4 != 0) — unused for N=4M but kept correct
    const int rem_start = n4 << 2;
    for (int i = rem_start + blockIdx.x * blockDim.x + tid; i < n; i += stride) {
        const int b = bucket_idx[i];
        const float4 prm = s_prm[b];
        float v = fmaf(x[i], prm.x, prm.y);
        v = fminf(fmaxf(v, prm.z), prm.w);
        float acc = s_awv[b][4].x;
        #pragma unroll
        for (int k = 0; k < KB; ++k)
            acc = fmaf(sbw[k], fminf(v, sbk[k]), acc);
        const float* aw = (const float*)&s_awv[b][0];
        #pragma unroll
        for (int k = 0; k < KA; ++k)
            acc = fmaf(aw[k], fminf(v, sak[k]), acc);
        out[i] = acc;
    }
}

extern "C" void kernel_launch(void* const* d_in, const int* in_sizes, int n_in,
                              void* d_out, int out_size, void* d_ws, size_t ws_size,
                              hipStream_t stream) {
    const float* x          = (const float*)d_in[0];
    const float* x_mins     = (const float*)d_in[1];
    const float* x_maxs     = (const float*)d_in[2];
    const float* clip_los   = (const float*)d_in[3];
    const float* clip_his   = (const float*)d_in[4];
    const float* base_knots = (const float*)d_in[5];
    const float* base_raw_w = (const float*)d_in[6];
    const float* base_bias  = (const float*)d_in[7];
    const float* adj_knots  = (const float*)d_in[8];
    const float* adj_raw_w  = (const float*)d_in[9];
    const float* adj_bias   = (const float*)d_in[10];
    const int*   bucket_idx = (const int*)d_in[11];
    float* out = (float*)d_out;

    const int n = in_sizes[0];
    const int blocks = 2048;   // 8 wg/CU at 256 threads; ~2 float4 iters/thread
    BucketAdjustedHinge_kernel<<<blocks, 256, 0, stream>>>(
        x, x_mins, x_maxs, clip_los, clip_his,
        base_knots, base_raw_w, base_bias,
        adj_knots, adj_raw_w, adj_bias,
        bucket_idx, out, n);
}

// Round 4
// 19.243 us; speedup vs baseline: 4.1403x; 4.1403x over previous
//
#include <hip/hip_runtime.h>
#include <math.h>

#define NB 16
#define KB 32
#define KA 16
#define G  128            // LUT cells per bucket
#define HINV ((float)G)
#define H (1.0f / (float)G)

// ws layout (floats):
//   [0 .. 64)              float4 prm[NB]   : {a, c, Lb, Hb} per bucket
//   [64 .. 64+2*NB*G)      float2 lut[NB*G] : {c0, c1} per cell; f(v) = c0 + c1*v
#define WS_FLOATS (64 + 2 * NB * G)

__device__ __forceinline__ float softplus_f(float v) {
    return fmaxf(v, 0.0f) + log1pf(expf(-fabsf(v)));
}

// ---------------- kernel 1: build per-bucket PWL coefficient table ----------------
// 8 blocks x 256 threads; block handles 2 buckets.
__global__ __launch_bounds__(256) void build_lut_kernel(
    const float* __restrict__ x_mins,
    const float* __restrict__ x_maxs,
    const float* __restrict__ clip_los,
    const float* __restrict__ clip_his,
    const float* __restrict__ base_knots,
    const float* __restrict__ base_raw_w,
    const float* __restrict__ base_bias,
    const float* __restrict__ adj_knots,
    const float* __restrict__ adj_raw_w,
    const float* __restrict__ adj_bias,
    float* __restrict__ ws)
{
    __shared__ float s_bw[KB];
    __shared__ float s_aw[2][KA];
    __shared__ float s_bias[2];
    __shared__ float s_f[2][G + 1];

    const int tid = threadIdx.x;
    const int b0  = blockIdx.x * 2;   // this block's first bucket

    if (tid < KB) s_bw[tid] = softplus_f(base_raw_w[tid]);
    if (tid < 2 * KA) {
        const int lb = tid / KA, k = tid % KA;
        s_aw[lb][k] = softplus_f(adj_raw_w[(b0 + lb) * KA + k]);
    }
    if (tid < 2) {
        const int b = b0 + tid;
        const float mn = x_mins[b], mx = x_maxs[b];
        const float a = 1.0f / (mx - mn + 1e-12f);
        const float c = -mn * a;
        const float lo = clip_los[b], hi = clip_his[b];
        // fold clip bounds through monotone affine map + [0,1] clamp;
        // non-finite bound => no clipping on that side
        const float Lb = isfinite(lo) ? fminf(fmaxf(fmaf(lo, a, c), 0.0f), 1.0f) : 0.0f;
        const float Hb = isfinite(hi) ? fmaxf(fminf(fmaf(hi, a, c), 1.0f), 0.0f) : 1.0f;
        ((float4*)ws)[b] = make_float4(a, c, Lb, Hb);
        s_bias[tid] = adj_bias[b] + base_bias[0];
    }
    __syncthreads();

    // exact f at gridpoints (PWL in v; exact regardless of knot positions)
    for (int gp = tid; gp < 2 * (G + 1); gp += 256) {
        const int lb = gp / (G + 1);
        const int j  = gp % (G + 1);
        const float g = (float)j * H;          // H = 2^-7, exact
        float f = s_bias[lb];
        #pragma unroll 8
        for (int k = 0; k < KB; ++k)
            f = fmaf(s_bw[k], fminf(g, base_knots[k]), f);
        #pragma unroll 8
        for (int k = 0; k < KA; ++k)
            f = fmaf(s_aw[lb][k], fminf(g, adj_knots[k]), f);
        s_f[lb][j] = f;
    }
    __syncthreads();

    float2* lut = (float2*)(ws + 64);
    if (tid < 2 * G) {
        const int lb = tid >> 7, cc = tid & (G - 1);
        const float fl = s_f[lb][cc], fr = s_f[lb][cc + 1];
        const float c1 = (fr - fl) * HINV;
        const float c0 = fmaf(-c1, (float)cc * H, fl);
        lut[(b0 + lb) * G + cc] = make_float2(c0, c1);
    }
}

// ---------------- kernel 2: streaming evaluation through the LDS LUT ----------------
__global__ __launch_bounds__(256) void BucketAdjustedHinge_kernel(
    const float* __restrict__ x,
    const int*   __restrict__ bucket_idx,
    const float* __restrict__ ws,
    float*       __restrict__ out,
    int n)
{
    __shared__ float s_mem[WS_FLOATS];    // prm[16] float4, then lut[2048] float2
    const float4* __restrict__ prmp = (const float4*)s_mem;
    const float2* __restrict__ lutp = (const float2*)(s_mem + 64);

    const int tid = threadIdx.x;

    // copy table from global scratch into LDS (L2-served; 1040 float4)
    {
        const float4* __restrict__ src = (const float4*)ws;
        float4* __restrict__ dst = (float4*)s_mem;
        #pragma unroll
        for (int i = 0; i < WS_FLOATS / 4 / 256 + 1; ++i) {
            const int idx = tid + i * 256;
            if (idx < WS_FLOATS / 4) dst[idx] = src[idx];
        }
    }
    __syncthreads();

    const int n4 = n >> 2;
    const int stride = gridDim.x * blockDim.x;
    const float4* __restrict__ x4v = (const float4*)x;
    const int4*   __restrict__ b4v = (const int4*)bucket_idx;
    float4*       __restrict__ o4v = (float4*)out;

    for (int i = blockIdx.x * blockDim.x + tid; i < n4; i += stride) {
        const float4 xv = x4v[i];
        const int4   bv = b4v[i];
        const float xs[4] = {xv.x, xv.y, xv.z, xv.w};
        const int   bs[4] = {bv.x, bv.y, bv.z, bv.w};
        float ox[4];
        #pragma unroll
        for (int j = 0; j < 4; ++j) {
            const int b = bs[j];
            const float4 prm = prmp[b];
            float v = fmaf(xs[j], prm.x, prm.y);
            v = fminf(fmaxf(v, prm.z), prm.w);        // v in [0,1]
            int cell = (int)(v * HINV);
            cell = min(cell, G - 1);
            const float2 cf = lutp[(b << 7) + cell];
            ox[j] = fmaf(v, cf.y, cf.x);
        }
        o4v[i] = make_float4(ox[0], ox[1], ox[2], ox[3]);
    }

    // tail (n % 4 != 0) — unused for N=4M but kept correct
    const int rem_start = n4 << 2;
    for (int i = rem_start + blockIdx.x * blockDim.x + tid; i < n; i += stride) {
        const int b = bucket_idx[i];
        const float4 prm = prmp[b];
        float v = fmaf(x[i], prm.x, prm.y);
        v = fminf(fmaxf(v, prm.z), prm.w);
        int cell = (int)(v * HINV);
        cell = min(cell, G - 1);
        const float2 cf = lutp[(b << 7) + cell];
        out[i] = fmaf(v, cf.y, cf.x);
    }
}

extern "C" void kernel_launch(void* const* d_in, const int* in_sizes, int n_in,
                              void* d_out, int out_size, void* d_ws, size_t ws_size,
                              hipStream_t stream) {
    const float* x          = (const float*)d_in[0];
    const float* x_mins     = (const float*)d_in[1];
    const float* x_maxs     = (const float*)d_in[2];
    const float* clip_los   = (const float*)d_in[3];
    const float* clip_his   = (const float*)d_in[4];
    const float* base_knots = (const float*)d_in[5];
    const float* base_raw_w = (const float*)d_in[6];
    const float* base_bias  = (const float*)d_in[7];
    const float* adj_knots  = (const float*)d_in[8];
    const float* adj_raw_w  = (const float*)d_in[9];
    const float* adj_bias   = (const float*)d_in[10];
    const int*   bucket_idx = (const int*)d_in[11];
    float* out = (float*)d_out;
    float* ws  = (float*)d_ws;

    const int n = in_sizes[0];

    build_lut_kernel<<<NB / 2, 256, 0, stream>>>(
        x_mins, x_maxs, clip_los, clip_his,
        base_knots, base_raw_w, base_bias,
        adj_knots, adj_raw_w, adj_bias, ws);

    const int blocks = 2048;   // 8 wg/CU resident; ~2 float4 iters/thread at N=4M
    BucketAdjustedHinge_kernel<<<blocks, 256, 0, stream>>>(
        x, bucket_idx, ws, out, n);
}